// Round 15
// baseline (331.253 us; speedup 1.0000x reference)
//
#include <hip/hip_runtime.h>

// B=8, S=1024, H=16, DK=64, D=1024. Inputs/outputs fp32. Internal bf16 MFMA.
// Q pre-scaled by log2(e)/8; exps raw v_exp_f32; masking additive -1e9.
// GLDS LDS tiles XOR-swizzled (chunk ^ ((row>>1)&3)); reads use
// quad ^ ((l15>>1)&3) -> conflicts 8-way -> 2-way (free).
// FINAL (R15). Session: 354.5 -> ~306us (-14%). What's IN: gemm dbuf
// prefetch; XCD remap (m204) on all MFMA kernels (gemm FETCH 200->85MB);
// R4 V-epilogue LDS transpose (qkv 122->~75us); R7 pv separate-__shared__
// arrays + QE alias (26.6KB, 6 blocks/CU); R9 prep merge; 16MB memcpy.
// R15 de-risk: qkv gemm proved BIMODAL (77 vs 90us/VGPR92) across
// compiles when the merged-out-proj branch lived in the <0,1> sibling
// (bad in R9/R14, good in R10/R12/R13; rule #19 sibling perturbation).
// With the exact R4-R8 template text: 5/5 runs good. So: byte-exact
// R4-R8 gemm template restored; out-proj = two launches (R4 launcher).
// Measured NULL: attn XCD remap on time (FETCH -6x, latency-bound),
// occupancy 4->6 blocks (+3%), QBLK/TBLK=128, setprio x3, depth-1/2
// gemm pipelining. Measured NEGATIVE: counted-vmcnt asm clobbers,
// one-pool LDS (alias loss), T14 reg-staging (~16% tax vs gload_lds).
// pv 77us floor = double-EXP2 serial chain; qkv ~75us = 2-phase/128-tile
// ceiling (687TF). Next steps beyond this structure: T12 swapped-QK
// in-register softmax; 8-phase 256-tile gemm port.

typedef unsigned short ushort_t;
typedef unsigned short us4 __attribute__((ext_vector_type(4)));
typedef unsigned short us8 __attribute__((ext_vector_type(8)));
typedef __bf16 bf16x8 __attribute__((ext_vector_type(8)));
typedef float f32x4 __attribute__((ext_vector_type(4)));

#define QSCALE 0.18033688011112042f  // log2(e)/8
#define LOG2E 1.4426950408889634f
#define MNEG (-1.0e9f)
#define EXP2(x) __builtin_amdgcn_exp2f(x)

__device__ __forceinline__ ushort_t f2bf(float f) {
    unsigned int u = __float_as_uint(f);
    return (ushort_t)((u + 0x7fffu + ((u >> 16) & 1u)) >> 16);  // RTNE
}

// bijective XCD chunk remap (m204): blocks sharing input panels get
// consecutive work ids -> same XCD -> panel stays in that XCD's L2.
__device__ __forceinline__ int xcd_remap() {
    int nwg = gridDim.x * gridDim.y * gridDim.z;
    int o = blockIdx.x + gridDim.x * (blockIdx.y + gridDim.y * blockIdx.z);
    int q = nwg >> 3, r = nwg & 7;
    int xcd = o & 7, i = o >> 3;
    return (xcd < r ? xcd * (q + 1) : r * (q + 1) + (xcd - r) * q) + i;
}

// async global->LDS, 16B/lane; LDS dst = wave-uniform base + lane*16
#define GLDS(gp, lp)                                                        \
    __builtin_amdgcn_global_load_lds(                                       \
        (const __attribute__((address_space(1))) unsigned int*)(gp),        \
        (__attribute__((address_space(3))) unsigned int*)(lp), 16, 0, 0)

#define MFMA(a, b, c) __builtin_amdgcn_mfma_f32_16x16x32_bf16((a), (b), (c), 0, 0, 0)

// ---------------- LayerNorm: x fp32 [8192][1024] -> xn bf16 ----------------
__global__ __launch_bounds__(256) void ln_kernel(const float* __restrict__ x,
                                                 ushort_t* __restrict__ xn) {
    int row = blockIdx.x, tid = threadIdx.x;
    float4 v = ((const float4*)(x + (size_t)row * 1024))[tid];
    float s = v.x + v.y + v.z + v.w;
    __shared__ float red[8];
    for (int o = 32; o > 0; o >>= 1) s += __shfl_down(s, o);
    int wave = tid >> 6, lane = tid & 63;
    if (lane == 0) red[wave] = s;
    __syncthreads();
    float mu = (red[0] + red[1] + red[2] + red[3]) * (1.0f / 1024.0f);
    float d0 = v.x - mu, d1 = v.y - mu, d2 = v.z - mu, d3 = v.w - mu;
    float q = d0 * d0 + d1 * d1 + d2 * d2 + d3 * d3;
    for (int o = 32; o > 0; o >>= 1) q += __shfl_down(q, o);
    if (lane == 0) red[wave + 4] = q;
    __syncthreads();
    float var = (red[4] + red[5] + red[6] + red[7]) * (1.0f / 1024.0f);
    float rs = rsqrtf(var + 1e-5f);
    us4 ov;
    ov[0] = f2bf(d0 * rs); ov[1] = f2bf(d1 * rs);
    ov[2] = f2bf(d2 * rs); ov[3] = f2bf(d3 * rs);
    ((us4*)(xn + (size_t)row * 1024))[tid] = ov;
}

// --- prep: LayerNorm (blocks [0,8192)) + 4x weight fp32->bf16 convert ------
// (blocks [8192,12288)) fused into one launch; branch is block-uniform.
__global__ __launch_bounds__(256) void prep(
    const float* __restrict__ x, ushort_t* __restrict__ xn,
    const float* __restrict__ s0, const float* __restrict__ s1,
    const float* __restrict__ s2, const float* __restrict__ s3,
    ushort_t* __restrict__ d0, ushort_t* __restrict__ d1,
    ushort_t* __restrict__ d2, ushort_t* __restrict__ d3) {
    int b = blockIdx.x, tid = threadIdx.x;
    if (b < 8192) {
        int row = b;
        float4 v = ((const float4*)(x + (size_t)row * 1024))[tid];
        float s = v.x + v.y + v.z + v.w;
        __shared__ float red[8];
        for (int o = 32; o > 0; o >>= 1) s += __shfl_down(s, o);
        int wave = tid >> 6, lane = tid & 63;
        if (lane == 0) red[wave] = s;
        __syncthreads();
        float mu = (red[0] + red[1] + red[2] + red[3]) * (1.0f / 1024.0f);
        float e0 = v.x - mu, e1 = v.y - mu, e2 = v.z - mu, e3 = v.w - mu;
        float q = e0 * e0 + e1 * e1 + e2 * e2 + e3 * e3;
        for (int o = 32; o > 0; o >>= 1) q += __shfl_down(q, o);
        if (lane == 0) red[wave + 4] = q;
        __syncthreads();
        float var = (red[4] + red[5] + red[6] + red[7]) * (1.0f / 1024.0f);
        float rs = rsqrtf(var + 1e-5f);
        us4 ov;
        ov[0] = f2bf(e0 * rs); ov[1] = f2bf(e1 * rs);
        ov[2] = f2bf(e2 * rs); ov[3] = f2bf(e3 * rs);
        ((us4*)(xn + (size_t)row * 1024))[tid] = ov;
    } else {
        int i = b - 8192;  // [0,4096): 4 tensors x 1024 blocks
        int sel = i >> 10, blk = i & 1023;
        const float* s = (sel == 0) ? s0 : (sel == 1) ? s1 : (sel == 2) ? s2 : s3;
        ushort_t* d = (sel == 0) ? d0 : (sel == 1) ? d1 : (sel == 2) ? d2 : d3;
        size_t idx = ((size_t)blk * 256 + tid) * 4;
        float4 f = *(const float4*)(s + idx);
        us4 o;
        o[0] = f2bf(f.x); o[1] = f2bf(f.y); o[2] = f2bf(f.z); o[3] = f2bf(f.w);
        *(us4*)(d + idx) = o;
    }
}

// ------------- bf16 tail copy: 128 rows (compact path only) ----------------
__global__ __launch_bounds__(256) void tailcopy(const us8* __restrict__ src,
                                                us8* __restrict__ dst) {
    size_t i = (size_t)blockIdx.x * 256 + threadIdx.x;  // 16384 us8
    dst[i] = src[i];
}

// --------- MFMA bt-GEMM: C[r][n] = sum_k A[r][k] * B[n][k] + bias[n] -------
// BMODE 0: B bf16 (async staged); 1: B fp32 (VALU convert staged)
// OMODE 0: qkv epilogue (q/k direct bf16 stores; v via LDS transpose)
// OMODE 1: fp32 out + residual; output row index shifted by osub
// BYTE-EXACT R4-R8 template (5/5 runs compiled the good <0,0> codegen;
// the merged-out-proj branch variant was bimodal: 90us/VGPR92 in 2/5).
template <int BMODE, int OMODE>
__global__ __launch_bounds__(256) void gemm_mfma(
    const ushort_t* __restrict__ A, const void* __restrict__ Bq,
    const void* __restrict__ Bk, const void* __restrict__ Bv,
    const float* __restrict__ biasq, const float* __restrict__ biask,
    const float* __restrict__ biasv, ushort_t* __restrict__ oq,
    ushort_t* __restrict__ ok, ushort_t* __restrict__ ovt,
    float* __restrict__ ofp, const float* __restrict__ resx, int batched,
    int r0base, int aoff, int osub) {
    // 2x(A)+2x(B) staging buffers; contiguous so the epilogue can reuse all
    // 32KB as a 128x128 bf16 transpose scratch.
    __shared__ ushort_t SMEM[4][128 * 32] __attribute__((aligned(16)));
#define AS_(b) (SMEM[(b)])
#define BS_(b) (SMEM[2 + (b)])
    int tid = threadIdx.x, w = tid >> 6, lane = tid & 63;
    int quad = lane >> 4, l15 = lane & 15;
    int wm = w & 1, wn = w >> 1;
    int csw = (quad ^ ((l15 >> 1) & 3)) * 8;  // swizzled chunk offset
    // panel-major decomposition of XCD-chunked work id: y outer, (z,x) inner
    int wg = xcd_remap();
    int gxz = gridDim.x * gridDim.z;
    int wy = wg / gxz, wt = wg % gxz;
    int n0 = (wt % gridDim.x) * 128;
    int r0 = r0base + wy * 128;
    int wsel = wt / gridDim.x;
    const void* Bp = (wsel == 0) ? Bq : (wsel == 1) ? Bk : Bv;
    const float* biasp = (wsel == 0) ? biasq : (wsel == 1) ? biask : biasv;
    const float qscale = (OMODE == 0 && wsel == 0) ? QSCALE : 1.0f;

    auto stage = [&](int buf, int k0) {
#pragma unroll
        for (int ii = 0; ii < 2; ii++) {  // A tile 128x32 (8KB)
            int li = (w * 2 + ii) * 64 + lane;
            int row = li >> 2, kc = li & 3;
            int sk = kc ^ ((row >> 1) & 3);
            GLDS(A + (size_t)(r0 + row - aoff) * 1024 + k0 + sk * 8,
                 &AS_(buf)[(w * 2 + ii) * 512]);
        }
        if (BMODE == 0) {
#pragma unroll
            for (int ii = 0; ii < 2; ii++) {
                int li = (w * 2 + ii) * 64 + lane;
                int row = li >> 2, kc = li & 3;
                int sk = kc ^ ((row >> 1) & 3);
                GLDS((const ushort_t*)Bp + (size_t)(n0 + row) * 1024 + k0 + sk * 8,
                     &BS_(buf)[(w * 2 + ii) * 512]);
            }
        } else {
            int row = tid >> 1, half = tid & 1;
            int sw = (row >> 1) & 3;
            const float* gb =
                (const float*)Bp + (size_t)(n0 + row) * 1024 + k0 + half * 16;
            float4 f0 = *(const float4*)gb;
            float4 f1 = *(const float4*)(gb + 4);
            float4 f2 = *(const float4*)(gb + 8);
            float4 f3 = *(const float4*)(gb + 12);
            us8 p0, p1;
            p0[0] = f2bf(f0.x); p0[1] = f2bf(f0.y); p0[2] = f2bf(f0.z); p0[3] = f2bf(f0.w);
            p0[4] = f2bf(f1.x); p0[5] = f2bf(f1.y); p0[6] = f2bf(f1.z); p0[7] = f2bf(f1.w);
            p1[0] = f2bf(f2.x); p1[1] = f2bf(f2.y); p1[2] = f2bf(f2.z); p1[3] = f2bf(f2.w);
            p1[4] = f2bf(f3.x); p1[5] = f2bf(f3.y); p1[6] = f2bf(f3.z); p1[7] = f2bf(f3.w);
            *(us8*)&BS_(buf)[row * 32 + ((half * 2) ^ sw) * 8] = p0;
            *(us8*)&BS_(buf)[row * 32 + ((half * 2 + 1) ^ sw) * 8] = p1;
        }
    };

    f32x4 acc[4][4];
    stage(0, 0);  // prologue: tile 0 in flight while acc zeroed
#pragma unroll
    for (int i = 0; i < 4; i++)
#pragma unroll
        for (int j = 0; j < 4; j++) acc[i][j] = (f32x4){0.f, 0.f, 0.f, 0.f};
    __syncthreads();

    int cur = 0;
    for (int k0 = 0; k0 < 1024; k0 += 32) {
        if (k0 + 32 < 1024) stage(cur ^ 1, k0 + 32);  // prefetch next tile
        bf16x8 a[4], b[4];
#pragma unroll
        for (int i = 0; i < 4; i++)
            a[i] = *(const bf16x8*)&AS_(cur)[(wm * 64 + i * 16 + l15) * 32 + csw];
#pragma unroll
        for (int j = 0; j < 4; j++)
            b[j] = *(const bf16x8*)&BS_(cur)[(wn * 64 + j * 16 + l15) * 32 + csw];
#pragma unroll
        for (int i = 0; i < 4; i++)
#pragma unroll
            for (int j = 0; j < 4; j++) acc[i][j] = MFMA(a[i], b[j], acc[i][j]);
        __syncthreads();  // drains this iter's prefetch; next tile ready
        cur ^= 1;
    }
    // epilogue; C layout: col=l15, row=quad*4+v
    if (OMODE == 0 && wsel == 2) {
        // V: transpose 128x128 tile through LDS -> 16B-contiguous global
        // stores (was 2B stores at 2KB stride). XOR swizzle (n&15)<<3 keeps
        // us8 chunks aligned and spreads banks.
        ushort_t* TP = &SMEM[0][0];
#pragma unroll
        for (int j = 0; j < 4; j++) {
            int nl = wn * 64 + j * 16 + l15;
            float bj = biasp[n0 + nl];
#pragma unroll
            for (int i = 0; i < 4; i++)
#pragma unroll
                for (int v = 0; v < 4; v++) {
                    int rl = wm * 64 + i * 16 + quad * 4 + v;
                    TP[nl * 128 + (rl ^ ((nl & 15) << 3))] =
                        f2bf(acc[i][j][v] + bj);
                }
        }
        __syncthreads();
        int row = tid >> 1, half = tid & 1;  // row = local n (out row)
        int n = n0 + row, hh = n >> 6, kk = n & 63;
        int bb = batched ? (r0 >> 10) : 0;
        int sbase = (r0 & 1023) + half * 64;
        ushort_t* gp = ovt + ((size_t)(bb * 16 + hh) * 64 + kk) * 1024 + sbase;
#pragma unroll
        for (int c = 0; c < 8; c++) {
            us8 vv = *(const us8*)&TP[row * 128 +
                                      ((half * 64 + c * 8) ^ ((row & 15) << 3))];
            *(us8*)(gp + c * 8) = vv;
        }
    } else {
#pragma unroll
        for (int j = 0; j < 4; j++) {
            int n = n0 + wn * 64 + j * 16 + l15;
            float bj = biasp[n];
            if (OMODE == 0) {
                int h = n >> 6, kk = n & 63;
#pragma unroll
                for (int i = 0; i < 4; i++) {
#pragma unroll
                    for (int v = 0; v < 4; v++) {
                        int r = r0 + wm * 64 + i * 16 + quad * 4 + v;
                        int bb = batched ? (r >> 10) : 0;
                        int s = r & 1023;
                        ushort_t val = f2bf((acc[i][j][v] + bj) * qscale);
                        ushort_t* op = (wsel == 0) ? oq : ok;
                        op[((size_t)(bb * 16 + h) * 1024 + s) * 64 + kk] = val;
                    }
                }
            } else {
#pragma unroll
                for (int i = 0; i < 4; i++) {
#pragma unroll
                    for (int v = 0; v < 4; v++) {
                        int r = r0 + wm * 64 + i * 16 + quad * 4 + v;
                        ofp[(size_t)(r - osub) * 1024 + n] =
                            acc[i][j][v] + bj + resx[(size_t)r * 1024 + n];
                    }
                }
            }
        }
    }
#undef AS_
#undef BS_
}

// --- colsum[bh][t] = sum_s exp(masked score) ; MFMA 64x64 tiles ------------
// Measured-best body + XCD remap (16 same-by blocks share qb panel).
__global__ __launch_bounds__(256) void colstats_mfma(
    const ushort_t* __restrict__ qb, const ushort_t* __restrict__ kb,
    const float* __restrict__ mask, int moff, float* __restrict__ colsum) {
    __shared__ ushort_t Ks[4096] __attribute__((aligned(16)));  // [2][64][32]
    __shared__ ushort_t Qs[4096] __attribute__((aligned(16)));
    __shared__ float mk[64], mq[64], red[4][64];
    int tid = threadIdx.x, w = tid >> 6, lane = tid & 63;
    int quad = lane >> 4, l15 = lane & 15;
    int csw = (quad ^ ((l15 >> 1) & 3)) * 8;
    int wg = xcd_remap();
    int by = wg / gridDim.x;
    int t0 = (wg % gridDim.x) * 64;
    size_t qoff = (size_t)by * 65536;
    int coff = by * 1024;
    int mb = moff + (by >> 4) * 1024;
#pragma unroll
    for (int ii = 0; ii < 2; ii++) {
        int qq = w * 2 + ii, half = qq >> 2, sub = qq & 3;
        int li = sub * 64 + lane, row = li >> 2, seg = li & 3;
        int sk = seg ^ ((row >> 1) & 3);
        GLDS(kb + qoff + (size_t)(t0 + row) * 64 + half * 32 + sk * 8,
             &Ks[half * 2048 + sub * 512]);
    }
    if (tid < 64) mk[tid] = mask[mb + t0 + tid];
    __syncthreads();
    // hoist K fragments (loop-invariant) into registers
    bf16x8 kf0[4], kf1[4];
#pragma unroll
    for (int j = 0; j < 4; j++) {
        kf0[j] = *(const bf16x8*)&Ks[(j * 16 + l15) * 32 + csw];
        kf1[j] = *(const bf16x8*)&Ks[2048 + (j * 16 + l15) * 32 + csw];
    }
    float amk[4];
#pragma unroll
    for (int j = 0; j < 4; j++) amk[j] = (mk[j * 16 + l15] > 0.f) ? 0.f : MNEG;
    float colacc[4] = {0.f, 0.f, 0.f, 0.f};
    for (int s0 = 0; s0 < 1024; s0 += 64) {
        __syncthreads();
#pragma unroll
        for (int ii = 0; ii < 2; ii++) {
            int qq = w * 2 + ii, half = qq >> 2, sub = qq & 3;
            int li = sub * 64 + lane, row = li >> 2, seg = li & 3;
            int sk = seg ^ ((row >> 1) & 3);
            GLDS(qb + qoff + (size_t)(s0 + row) * 64 + half * 32 + sk * 8,
                 &Qs[half * 2048 + sub * 512]);
        }
        if (tid < 64) mq[tid] = mask[mb + s0 + tid];
        __syncthreads();
        float amq[4];
#pragma unroll
        for (int v = 0; v < 4; v++)
            amq[v] = (mq[w * 16 + quad * 4 + v] > 0.f) ? 0.f : MNEG;
        bf16x8 a0 = *(const bf16x8*)&Qs[(w * 16 + l15) * 32 + csw];
        bf16x8 a1 = *(const bf16x8*)&Qs[2048 + (w * 16 + l15) * 32 + csw];
#pragma unroll
        for (int j = 0; j < 4; j++) {
            f32x4 sc = (f32x4){0.f, 0.f, 0.f, 0.f};
            sc = MFMA(a0, kf0[j], sc);
            sc = MFMA(a1, kf1[j], sc);
#pragma unroll
            for (int v = 0; v < 4; v++)
                colacc[j] += EXP2(sc[v] + amq[v] + amk[j]);
        }
    }
#pragma unroll
    for (int j = 0; j < 4; j++) {
        float vv = colacc[j];
        vv += __shfl_down(vv, 32);
        vv += __shfl_down(vv, 16);
        if (quad == 0) red[w][j * 16 + l15] = vv;
    }
    __syncthreads();
    if (tid < 64)
        colsum[coff + t0 + tid] = red[0][tid] + red[1][tid] + red[2][tid] + red[3][tid];
}

// --- double softmax + PV (MFMA); heads bf16, single base -------------------
// Measured-best body (separate __shared__ arrays, QE alias, GLDS staging).
#define ESTR 72
__global__ __launch_bounds__(256) void pv_mfma(
    const ushort_t* __restrict__ qb, const ushort_t* __restrict__ kb,
    const ushort_t* __restrict__ vtb, const float* __restrict__ mask, int moff,
    const float* __restrict__ colsum, ushort_t* __restrict__ H, int hbase) {
    __shared__ ushort_t Ks[4096] __attribute__((aligned(16)));
    __shared__ ushort_t Vt[4096] __attribute__((aligned(16)));  // [2][64dk][32t]
    __shared__ ushort_t QE[64 * ESTR] __attribute__((aligned(16)));
    __shared__ float mk[64], mq[64], ics[64];
    int tid = threadIdx.x, w = tid >> 6, lane = tid & 63;
    int quad = lane >> 4, l15 = lane & 15;
    int csw = (quad ^ ((l15 >> 1) & 3)) * 8;
    int wg = xcd_remap();
    int by = wg / gridDim.x;
    int s0 = (wg % gridDim.x) * 64;
    size_t qoff = (size_t)by * 65536;
    int coff = by * 1024;
    int mb = moff + (by >> 4) * 1024;
    int h = by & 15;
#pragma unroll
    for (int ii = 0; ii < 2; ii++) {
        int qq = w * 2 + ii, half = qq >> 2, sub = qq & 3;
        int li = sub * 64 + lane, row = li >> 2, seg = li & 3;
        int sk = seg ^ ((row >> 1) & 3);
        GLDS(qb + qoff + (size_t)(s0 + row) * 64 + half * 32 + sk * 8,
             &QE[half * 2048 + sub * 512]);
    }
    if (tid < 64) mq[tid] = mask[mb + s0 + tid];
    __syncthreads();
    // hoist Q fragments (loop-invariant); QE's Q contents dead after this
    bf16x8 a0 = *(const bf16x8*)&QE[(w * 16 + l15) * 32 + csw];
    bf16x8 a1 = *(const bf16x8*)&QE[2048 + (w * 16 + l15) * 32 + csw];
    float amq[4];
#pragma unroll
    for (int v = 0; v < 4; v++)
        amq[v] = (mq[w * 16 + quad * 4 + v] > 0.f) ? 0.f : MNEG;
    bf16x8 ones;
#pragma unroll
    for (int e = 0; e < 8; e++) ones[e] = (__bf16)1.0f;
    f32x4 acc_o[4], acc_rs = (f32x4){0.f, 0.f, 0.f, 0.f};
#pragma unroll
    for (int j = 0; j < 4; j++) acc_o[j] = (f32x4){0.f, 0.f, 0.f, 0.f};
    for (int t0 = 0; t0 < 1024; t0 += 64) {
        __syncthreads();
#pragma unroll
        for (int ii = 0; ii < 2; ii++) {
            int qq = w * 2 + ii, half = qq >> 2, sub = qq & 3;
            int li = sub * 64 + lane, row = li >> 2, seg = li & 3;
            int sk = seg ^ ((row >> 1) & 3);
            GLDS(kb + qoff + (size_t)(t0 + row) * 64 + half * 32 + sk * 8,
                 &Ks[half * 2048 + sub * 512]);
            GLDS(vtb + qoff + (size_t)row * 1024 + t0 + half * 32 + sk * 8,
                 &Vt[half * 2048 + sub * 512]);
        }
        if (tid < 64) {
            mk[tid] = mask[mb + t0 + tid];
            float cs = colsum[coff + t0 + tid];
            ics[tid] = (cs > 0.f) ? LOG2E / cs : 0.f;
        }
        __syncthreads();
#pragma unroll
        for (int j = 0; j < 4; j++) {
            bf16x8 b0 = *(const bf16x8*)&Ks[(j * 16 + l15) * 32 + csw];
            bf16x8 b1 = *(const bf16x8*)&Ks[2048 + (j * 16 + l15) * 32 + csw];
            f32x4 sc = (f32x4){0.f, 0.f, 0.f, 0.f};
            sc = MFMA(a0, b0, sc);
            sc = MFMA(a1, b1, sc);
            int tcol = j * 16 + l15;
            float icv = ics[tcol];
            float aj = (mk[tcol] > 0.f) ? 0.f : MNEG;
#pragma unroll
            for (int v = 0; v < 4; v++) {
                float e1 = EXP2(sc[v]);                       // exp(score/8)
                float e2 = EXP2(fmaf(e1, icv, amq[v] + aj));  // exp(attn1) or 0
                int sl = w * 16 + quad * 4 + v;
                QE[sl * ESTR + tcol] = (ushort_t)(__float_as_uint(e2) >> 16);
            }
        }
        // PV: each wave reads only its own 16-row E strip (same-wave LDS order)
        bf16x8 ea0 = *(const bf16x8*)&QE[(w * 16 + l15) * ESTR + quad * 8];
        bf16x8 ea1 = *(const bf16x8*)&QE[(w * 16 + l15) * ESTR + 32 + quad * 8];
#pragma unroll
        for (int j = 0; j < 4; j++) {
            bf16x8 b0 = *(const bf16x8*)&Vt[(j * 16 + l15) * 32 + csw];
            bf16x8 b1 = *(const bf16x8*)&Vt[2048 + (j * 16 + l15) * 32 + csw];
            acc_o[j] = MFMA(ea0, b0, acc_o[j]);
            acc_o[j] = MFMA(ea1, b1, acc_o[j]);
        }
        acc_rs = MFMA(ea0, ones, acc_rs);
        acc_rs = MFMA(ea1, ones, acc_rs);
    }
#pragma unroll
    for (int v = 0; v < 4; v++) {
        int sl = w * 16 + quad * 4 + v;
        int hr = hbase + (by >> 4) * 1024 + s0 + sl;
        ushort_t* hp = H + (size_t)hr * 1024;
        float inv = 1.0f / fmaxf(acc_rs[v], 1e-30f);
#pragma unroll
        for (int j = 0; j < 4; j++)
            hp[h * 64 + j * 16 + l15] = f2bf(acc_o[j][v] * inv);
    }
}

extern "C" void kernel_launch(void* const* d_in, const int* in_sizes, int n_in,
                              void* d_out, int out_size, void* d_ws, size_t ws_size,
                              hipStream_t stream) {
    const float* x     = (const float*)d_in[0];
    const float* mask  = (const float*)d_in[1];
    const float* wq    = (const float*)d_in[2];
    const float* bq    = (const float*)d_in[3];
    const float* wk    = (const float*)d_in[4];
    const float* bk    = (const float*)d_in[5];
    const float* wv    = (const float*)d_in[6];
    const float* bv    = (const float*)d_in[7];
    const float* w_out = (const float*)d_in[8];
    const float* b_out = (const float*)d_in[9];
    float* outp = (float*)d_out;

    const size_t MB = 1024 * 1024;
    ushort_t* xn = (ushort_t*)d_out;             // bytes [0,16MB), dead after qkv
    ushort_t* H  = (ushort_t*)d_out + 8 * MB;    // heads bf16, bytes [16MB,32MB)
    char* ws = (char*)d_ws;

    if (ws_size >= 58 * MB) {
        ushort_t* qb  = (ushort_t*)ws;             // 16 MB (dead after pv)
        ushort_t* kb  = (ushort_t*)(ws + 16 * MB); // 16 MB (dead after pv)
        ushort_t* vtb = (ushort_t*)(ws + 32 * MB); // 16 MB
        float* csum   = (float*)(ws + 48 * MB);    // 512 KB
        ushort_t* wqb = (ushort_t*)(ws + 49 * MB);
        ushort_t* wkb = (ushort_t*)(ws + 51 * MB);
        ushort_t* wvb = (ushort_t*)(ws + 53 * MB);
        ushort_t* wob = (ushort_t*)(ws + 55 * MB);
        float* ohi    = (float*)ws;                // 16 MB: out rows [4096,8192)
        prep<<<dim3(12288), 256, 0, stream>>>(x, xn, wq, wk, wv, w_out,
                                              wqb, wkb, wvb, wob);
        gemm_mfma<0, 0><<<dim3(8, 64, 3), 256, 0, stream>>>(
            xn, wqb, wkb, wvb, bq, bk, bv, qb, kb, vtb, nullptr, nullptr, 1,
            0, 0, 0);
        colstats_mfma<<<dim3(16, 128), 256, 0, stream>>>(qb, kb, mask, 0, csum);
        pv_mfma<<<dim3(16, 128), 256, 0, stream>>>(qb, kb, vtb, mask, 0, csum, H, 0);
        // out-proj rows [0,4096): write d_out directly (xn dead, no H overlap)
        gemm_mfma<0, 1><<<dim3(8, 32), 256, 0, stream>>>(
            H, wob, wob, wob, b_out, b_out, b_out, nullptr, nullptr, nullptr,
            (float*)d_out, x, 0, 0, 0, 0);
        // out-proj rows [4096,8192): via ws (qb dead), then 16MB copy over H
        gemm_mfma<0, 1><<<dim3(8, 32), 256, 0, stream>>>(
            H, wob, wob, wob, b_out, b_out, b_out, nullptr, nullptr, nullptr,
            ohi, x, 0, 4096, 0, 4096);
        hipMemcpyAsync((char*)d_out + 16 * MB, ws, 16 * MB,
                       hipMemcpyDeviceToDevice, stream);
    } else {
        // compact path: <= 6.07 MB ws; in-place cascade out-proj
        ushort_t* qb  = (ushort_t*)ws;            // 2 MB
        ushort_t* kb  = (ushort_t*)(ws + 2 * MB); // 2 MB
        ushort_t* vtb = (ushort_t*)(ws + 4 * MB); // 2 MB
        float* csum   = (float*)(ws + 6 * MB);    // 64 KB
        ushort_t* hcopy = (ushort_t*)ws;          // 256KB tail copy (qb dead)
        const int casc[6][2] = {{0, 32},   {4096, 16}, {6144, 8},
                                {7168, 4}, {7680, 2},  {7936, 1}};
        ln_kernel<<<dim3(8192), 256, 0, stream>>>(x, xn);
        for (int g = 0; g < 8; g++) {
            gemm_mfma<1, 0><<<dim3(8, 8, 3), 256, 0, stream>>>(
                xn + (size_t)g * MB, wq, wk, wv, bq, bk, bv, qb, kb, vtb,
                nullptr, nullptr, 0, 0, 0, 0);
            colstats_mfma<<<dim3(16, 16), 256, 0, stream>>>(qb, kb, mask,
                                                            g * 1024, csum);
            pv_mfma<<<dim3(16, 16), 256, 0, stream>>>(qb, kb, vtb, mask,
                                                      g * 1024, csum, H, g * 1024);
        }
        tailcopy<<<dim3(64), 256, 0, stream>>>((const us8*)(H + (size_t)8064 * 1024),
                                               (us8*)hcopy);
        for (int i = 0; i < 6; i++)
            gemm_mfma<1, 1><<<dim3(8, casc[i][1]), 256, 0, stream>>>(
                H, w_out, w_out, w_out, b_out, b_out, b_out, nullptr, nullptr,
                nullptr, outp, x, 0, casc[i][0], 0, 0);
        gemm_mfma<1, 1><<<dim3(8, 1), 256, 0, stream>>>(
            hcopy, w_out, w_out, w_out, b_out, b_out, b_out, nullptr, nullptr,
            nullptr, outp, x, 0, 8064, 8064, 0);
    }
}

// Round 16
// 319.871 us; speedup vs baseline: 1.0356x; 1.0356x over previous
//
#include <hip/hip_runtime.h>

// B=8, S=1024, H=16, DK=64, D=1024. Inputs/outputs fp32. Internal bf16 MFMA.
// Q pre-scaled by log2(e)/8; exps raw v_exp_f32; masking additive -1e9.
// GLDS LDS tiles XOR-swizzled (chunk ^ ((row>>1)&3)); reads use
// quad ^ ((l15>>1)&3) -> conflicts 8-way -> 2-way (free).
// FINAL (R16). Session best 306.1us (from 354.5, -14%). Structure:
// prep (ln + 4x wconv merged) -> qkv gemm (2-phase dbuf, XCD remap,
// V-epilogue LDS transpose) -> colstats -> pv (QE alias, 6 blocks/CU)
// -> MERGED out-proj (ONE 8x64 launch, 2 blocks/CU) -> 16MB memcpy.
// R15 lesson: split out-proj (2x 8x32 = 1 block/CU each, two tails) costs
// ~20us vs merged (R7/R8/R15 329-331 vs R10/R12/R13 306-310) -- the merge,
// not the gemm codegen, was most of R10's win. R16 gets the merge WITHOUT
// the template-sibling bimodality (R9/R14 90us/VGPR92 mode, ~40% incidence
// when the split branch lived in the shared template): gemm_mfma is
// byte-exact R4-R8 (5/5-good record) and the merged out-proj is a
// STANDALONE kernel gemm_out (independent function, like prep).
// Measured NULL: attn XCD remap on time, occ 4->6 (+3%), QBLK/TBLK=128,
// setprio x3, depth-1/2 gemm pipelining. Measured NEGATIVE: counted-vmcnt
// asm clobbers, one-pool LDS (alias loss), T14 reg-staging (~16% tax).
// pv 77us floor = double-EXP2 serial chain; qkv ~75us = 2-phase/128-tile
// ceiling (687TF). Beyond this structure: T12 swapped-QK, 8-phase 256-tile.

typedef unsigned short ushort_t;
typedef unsigned short us4 __attribute__((ext_vector_type(4)));
typedef unsigned short us8 __attribute__((ext_vector_type(8)));
typedef __bf16 bf16x8 __attribute__((ext_vector_type(8)));
typedef float f32x4 __attribute__((ext_vector_type(4)));

#define QSCALE 0.18033688011112042f  // log2(e)/8
#define LOG2E 1.4426950408889634f
#define MNEG (-1.0e9f)
#define EXP2(x) __builtin_amdgcn_exp2f(x)

__device__ __forceinline__ ushort_t f2bf(float f) {
    unsigned int u = __float_as_uint(f);
    return (ushort_t)((u + 0x7fffu + ((u >> 16) & 1u)) >> 16);  // RTNE
}

// bijective XCD chunk remap (m204): blocks sharing input panels get
// consecutive work ids -> same XCD -> panel stays in that XCD's L2.
__device__ __forceinline__ int xcd_remap() {
    int nwg = gridDim.x * gridDim.y * gridDim.z;
    int o = blockIdx.x + gridDim.x * (blockIdx.y + gridDim.y * blockIdx.z);
    int q = nwg >> 3, r = nwg & 7;
    int xcd = o & 7, i = o >> 3;
    return (xcd < r ? xcd * (q + 1) : r * (q + 1) + (xcd - r) * q) + i;
}

// async global->LDS, 16B/lane; LDS dst = wave-uniform base + lane*16
#define GLDS(gp, lp)                                                        \
    __builtin_amdgcn_global_load_lds(                                       \
        (const __attribute__((address_space(1))) unsigned int*)(gp),        \
        (__attribute__((address_space(3))) unsigned int*)(lp), 16, 0, 0)

#define MFMA(a, b, c) __builtin_amdgcn_mfma_f32_16x16x32_bf16((a), (b), (c), 0, 0, 0)

// ---------------- LayerNorm: x fp32 [8192][1024] -> xn bf16 ----------------
__global__ __launch_bounds__(256) void ln_kernel(const float* __restrict__ x,
                                                 ushort_t* __restrict__ xn) {
    int row = blockIdx.x, tid = threadIdx.x;
    float4 v = ((const float4*)(x + (size_t)row * 1024))[tid];
    float s = v.x + v.y + v.z + v.w;
    __shared__ float red[8];
    for (int o = 32; o > 0; o >>= 1) s += __shfl_down(s, o);
    int wave = tid >> 6, lane = tid & 63;
    if (lane == 0) red[wave] = s;
    __syncthreads();
    float mu = (red[0] + red[1] + red[2] + red[3]) * (1.0f / 1024.0f);
    float d0 = v.x - mu, d1 = v.y - mu, d2 = v.z - mu, d3 = v.w - mu;
    float q = d0 * d0 + d1 * d1 + d2 * d2 + d3 * d3;
    for (int o = 32; o > 0; o >>= 1) q += __shfl_down(q, o);
    if (lane == 0) red[wave + 4] = q;
    __syncthreads();
    float var = (red[4] + red[5] + red[6] + red[7]) * (1.0f / 1024.0f);
    float rs = rsqrtf(var + 1e-5f);
    us4 ov;
    ov[0] = f2bf(d0 * rs); ov[1] = f2bf(d1 * rs);
    ov[2] = f2bf(d2 * rs); ov[3] = f2bf(d3 * rs);
    ((us4*)(xn + (size_t)row * 1024))[tid] = ov;
}

// --- prep: LayerNorm (blocks [0,8192)) + 4x weight fp32->bf16 convert ------
// (blocks [8192,12288)) fused into one launch; branch is block-uniform.
__global__ __launch_bounds__(256) void prep(
    const float* __restrict__ x, ushort_t* __restrict__ xn,
    const float* __restrict__ s0, const float* __restrict__ s1,
    const float* __restrict__ s2, const float* __restrict__ s3,
    ushort_t* __restrict__ d0, ushort_t* __restrict__ d1,
    ushort_t* __restrict__ d2, ushort_t* __restrict__ d3) {
    int b = blockIdx.x, tid = threadIdx.x;
    if (b < 8192) {
        int row = b;
        float4 v = ((const float4*)(x + (size_t)row * 1024))[tid];
        float s = v.x + v.y + v.z + v.w;
        __shared__ float red[8];
        for (int o = 32; o > 0; o >>= 1) s += __shfl_down(s, o);
        int wave = tid >> 6, lane = tid & 63;
        if (lane == 0) red[wave] = s;
        __syncthreads();
        float mu = (red[0] + red[1] + red[2] + red[3]) * (1.0f / 1024.0f);
        float e0 = v.x - mu, e1 = v.y - mu, e2 = v.z - mu, e3 = v.w - mu;
        float q = e0 * e0 + e1 * e1 + e2 * e2 + e3 * e3;
        for (int o = 32; o > 0; o >>= 1) q += __shfl_down(q, o);
        if (lane == 0) red[wave + 4] = q;
        __syncthreads();
        float var = (red[4] + red[5] + red[6] + red[7]) * (1.0f / 1024.0f);
        float rs = rsqrtf(var + 1e-5f);
        us4 ov;
        ov[0] = f2bf(e0 * rs); ov[1] = f2bf(e1 * rs);
        ov[2] = f2bf(e2 * rs); ov[3] = f2bf(e3 * rs);
        ((us4*)(xn + (size_t)row * 1024))[tid] = ov;
    } else {
        int i = b - 8192;  // [0,4096): 4 tensors x 1024 blocks
        int sel = i >> 10, blk = i & 1023;
        const float* s = (sel == 0) ? s0 : (sel == 1) ? s1 : (sel == 2) ? s2 : s3;
        ushort_t* d = (sel == 0) ? d0 : (sel == 1) ? d1 : (sel == 2) ? d2 : d3;
        size_t idx = ((size_t)blk * 256 + tid) * 4;
        float4 f = *(const float4*)(s + idx);
        us4 o;
        o[0] = f2bf(f.x); o[1] = f2bf(f.y); o[2] = f2bf(f.z); o[3] = f2bf(f.w);
        *(us4*)(d + idx) = o;
    }
}

// ------------- bf16 tail copy: 128 rows (compact path only) ----------------
__global__ __launch_bounds__(256) void tailcopy(const us8* __restrict__ src,
                                                us8* __restrict__ dst) {
    size_t i = (size_t)blockIdx.x * 256 + threadIdx.x;  // 16384 us8
    dst[i] = src[i];
}

// --------- MFMA bt-GEMM: C[r][n] = sum_k A[r][k] * B[n][k] + bias[n] -------
// BMODE 0: B bf16 (async staged); 1: B fp32 (VALU convert staged)
// OMODE 0: qkv epilogue (q/k direct bf16 stores; v via LDS transpose)
// OMODE 1: fp32 out + residual; output row index shifted by osub
// BYTE-EXACT R4-R8 template (5/5 runs compiled the good <0,0> codegen).
template <int BMODE, int OMODE>
__global__ __launch_bounds__(256) void gemm_mfma(
    const ushort_t* __restrict__ A, const void* __restrict__ Bq,
    const void* __restrict__ Bk, const void* __restrict__ Bv,
    const float* __restrict__ biasq, const float* __restrict__ biask,
    const float* __restrict__ biasv, ushort_t* __restrict__ oq,
    ushort_t* __restrict__ ok, ushort_t* __restrict__ ovt,
    float* __restrict__ ofp, const float* __restrict__ resx, int batched,
    int r0base, int aoff, int osub) {
    // 2x(A)+2x(B) staging buffers; contiguous so the epilogue can reuse all
    // 32KB as a 128x128 bf16 transpose scratch.
    __shared__ ushort_t SMEM[4][128 * 32] __attribute__((aligned(16)));
#define AS_(b) (SMEM[(b)])
#define BS_(b) (SMEM[2 + (b)])
    int tid = threadIdx.x, w = tid >> 6, lane = tid & 63;
    int quad = lane >> 4, l15 = lane & 15;
    int wm = w & 1, wn = w >> 1;
    int csw = (quad ^ ((l15 >> 1) & 3)) * 8;  // swizzled chunk offset
    // panel-major decomposition of XCD-chunked work id: y outer, (z,x) inner
    int wg = xcd_remap();
    int gxz = gridDim.x * gridDim.z;
    int wy = wg / gxz, wt = wg % gxz;
    int n0 = (wt % gridDim.x) * 128;
    int r0 = r0base + wy * 128;
    int wsel = wt / gridDim.x;
    const void* Bp = (wsel == 0) ? Bq : (wsel == 1) ? Bk : Bv;
    const float* biasp = (wsel == 0) ? biasq : (wsel == 1) ? biask : biasv;
    const float qscale = (OMODE == 0 && wsel == 0) ? QSCALE : 1.0f;

    auto stage = [&](int buf, int k0) {
#pragma unroll
        for (int ii = 0; ii < 2; ii++) {  // A tile 128x32 (8KB)
            int li = (w * 2 + ii) * 64 + lane;
            int row = li >> 2, kc = li & 3;
            int sk = kc ^ ((row >> 1) & 3);
            GLDS(A + (size_t)(r0 + row - aoff) * 1024 + k0 + sk * 8,
                 &AS_(buf)[(w * 2 + ii) * 512]);
        }
        if (BMODE == 0) {
#pragma unroll
            for (int ii = 0; ii < 2; ii++) {
                int li = (w * 2 + ii) * 64 + lane;
                int row = li >> 2, kc = li & 3;
                int sk = kc ^ ((row >> 1) & 3);
                GLDS((const ushort_t*)Bp + (size_t)(n0 + row) * 1024 + k0 + sk * 8,
                     &BS_(buf)[(w * 2 + ii) * 512]);
            }
        } else {
            int row = tid >> 1, half = tid & 1;
            int sw = (row >> 1) & 3;
            const float* gb =
                (const float*)Bp + (size_t)(n0 + row) * 1024 + k0 + half * 16;
            float4 f0 = *(const float4*)gb;
            float4 f1 = *(const float4*)(gb + 4);
            float4 f2 = *(const float4*)(gb + 8);
            float4 f3 = *(const float4*)(gb + 12);
            us8 p0, p1;
            p0[0] = f2bf(f0.x); p0[1] = f2bf(f0.y); p0[2] = f2bf(f0.z); p0[3] = f2bf(f0.w);
            p0[4] = f2bf(f1.x); p0[5] = f2bf(f1.y); p0[6] = f2bf(f1.z); p0[7] = f2bf(f1.w);
            p1[0] = f2bf(f2.x); p1[1] = f2bf(f2.y); p1[2] = f2bf(f2.z); p1[3] = f2bf(f2.w);
            p1[4] = f2bf(f3.x); p1[5] = f2bf(f3.y); p1[6] = f2bf(f3.z); p1[7] = f2bf(f3.w);
            *(us8*)&BS_(buf)[row * 32 + ((half * 2) ^ sw) * 8] = p0;
            *(us8*)&BS_(buf)[row * 32 + ((half * 2 + 1) ^ sw) * 8] = p1;
        }
    };

    f32x4 acc[4][4];
    stage(0, 0);  // prologue: tile 0 in flight while acc zeroed
#pragma unroll
    for (int i = 0; i < 4; i++)
#pragma unroll
        for (int j = 0; j < 4; j++) acc[i][j] = (f32x4){0.f, 0.f, 0.f, 0.f};
    __syncthreads();

    int cur = 0;
    for (int k0 = 0; k0 < 1024; k0 += 32) {
        if (k0 + 32 < 1024) stage(cur ^ 1, k0 + 32);  // prefetch next tile
        bf16x8 a[4], b[4];
#pragma unroll
        for (int i = 0; i < 4; i++)
            a[i] = *(const bf16x8*)&AS_(cur)[(wm * 64 + i * 16 + l15) * 32 + csw];
#pragma unroll
        for (int j = 0; j < 4; j++)
            b[j] = *(const bf16x8*)&BS_(cur)[(wn * 64 + j * 16 + l15) * 32 + csw];
#pragma unroll
        for (int i = 0; i < 4; i++)
#pragma unroll
            for (int j = 0; j < 4; j++) acc[i][j] = MFMA(a[i], b[j], acc[i][j]);
        __syncthreads();  // drains this iter's prefetch; next tile ready
        cur ^= 1;
    }
    // epilogue; C layout: col=l15, row=quad*4+v
    if (OMODE == 0 && wsel == 2) {
        // V: transpose 128x128 tile through LDS -> 16B-contiguous global
        // stores (was 2B stores at 2KB stride). XOR swizzle (n&15)<<3 keeps
        // us8 chunks aligned and spreads banks.
        ushort_t* TP = &SMEM[0][0];
#pragma unroll
        for (int j = 0; j < 4; j++) {
            int nl = wn * 64 + j * 16 + l15;
            float bj = biasp[n0 + nl];
#pragma unroll
            for (int i = 0; i < 4; i++)
#pragma unroll
                for (int v = 0; v < 4; v++) {
                    int rl = wm * 64 + i * 16 + quad * 4 + v;
                    TP[nl * 128 + (rl ^ ((nl & 15) << 3))] =
                        f2bf(acc[i][j][v] + bj);
                }
        }
        __syncthreads();
        int row = tid >> 1, half = tid & 1;  // row = local n (out row)
        int n = n0 + row, hh = n >> 6, kk = n & 63;
        int bb = batched ? (r0 >> 10) : 0;
        int sbase = (r0 & 1023) + half * 64;
        ushort_t* gp = ovt + ((size_t)(bb * 16 + hh) * 64 + kk) * 1024 + sbase;
#pragma unroll
        for (int c = 0; c < 8; c++) {
            us8 vv = *(const us8*)&TP[row * 128 +
                                      ((half * 64 + c * 8) ^ ((row & 15) << 3))];
            *(us8*)(gp + c * 8) = vv;
        }
    } else {
#pragma unroll
        for (int j = 0; j < 4; j++) {
            int n = n0 + wn * 64 + j * 16 + l15;
            float bj = biasp[n];
            if (OMODE == 0) {
                int h = n >> 6, kk = n & 63;
#pragma unroll
                for (int i = 0; i < 4; i++) {
#pragma unroll
                    for (int v = 0; v < 4; v++) {
                        int r = r0 + wm * 64 + i * 16 + quad * 4 + v;
                        int bb = batched ? (r >> 10) : 0;
                        int s = r & 1023;
                        ushort_t val = f2bf((acc[i][j][v] + bj) * qscale);
                        ushort_t* op = (wsel == 0) ? oq : ok;
                        op[((size_t)(bb * 16 + h) * 1024 + s) * 64 + kk] = val;
                    }
                }
            } else {
#pragma unroll
                for (int i = 0; i < 4; i++) {
#pragma unroll
                    for (int v = 0; v < 4; v++) {
                        int r = r0 + wm * 64 + i * 16 + quad * 4 + v;
                        ofp[(size_t)(r - osub) * 1024 + n] =
                            acc[i][j][v] + bj + resx[(size_t)r * 1024 + n];
                    }
                }
            }
        }
    }
#undef AS_
#undef BS_
}

// --- standalone merged out-proj: C[r][n]=sum_k H[r][k]*W[n][k]+b[n]+x[r][n]
// rows<4096 -> o_lo@r (d_out), rows>=4096 -> o_hi@(r-4096) (ws). One 8x64
// launch (2 blocks/CU). Independent kernel so the gemm_mfma template keeps
// its byte-exact R4-R8 instantiation context (rule #19 de-risk).
__global__ __launch_bounds__(256) void gemm_out(
    const ushort_t* __restrict__ A, const ushort_t* __restrict__ B,
    const float* __restrict__ bias, float* __restrict__ o_lo,
    float* __restrict__ o_hi, const float* __restrict__ resx) {
    __shared__ ushort_t As[2][128 * 32] __attribute__((aligned(16)));
    __shared__ ushort_t Bs[2][128 * 32] __attribute__((aligned(16)));
    int tid = threadIdx.x, w = tid >> 6, lane = tid & 63;
    int quad = lane >> 4, l15 = lane & 15;
    int wm = w & 1, wn = w >> 1;
    int csw = (quad ^ ((l15 >> 1) & 3)) * 8;
    int wg = xcd_remap();  // grid (8,64): y outer = row panel, x inner = n
    int wy = wg >> 3;
    int n0 = (wg & 7) * 128;
    int r0 = wy * 128;

    auto stage = [&](int buf, int k0) {
#pragma unroll
        for (int ii = 0; ii < 2; ii++) {
            int li = (w * 2 + ii) * 64 + lane;
            int row = li >> 2, kc = li & 3;
            int sk = kc ^ ((row >> 1) & 3);
            GLDS(A + (size_t)(r0 + row) * 1024 + k0 + sk * 8,
                 &As[buf][(w * 2 + ii) * 512]);
            GLDS(B + (size_t)(n0 + row) * 1024 + k0 + sk * 8,
                 &Bs[buf][(w * 2 + ii) * 512]);
        }
    };

    f32x4 acc[4][4];
    stage(0, 0);
#pragma unroll
    for (int i = 0; i < 4; i++)
#pragma unroll
        for (int j = 0; j < 4; j++) acc[i][j] = (f32x4){0.f, 0.f, 0.f, 0.f};
    __syncthreads();

    int cur = 0;
    for (int k0 = 0; k0 < 1024; k0 += 32) {
        if (k0 + 32 < 1024) stage(cur ^ 1, k0 + 32);
        bf16x8 a[4], b[4];
#pragma unroll
        for (int i = 0; i < 4; i++)
            a[i] = *(const bf16x8*)&As[cur][(wm * 64 + i * 16 + l15) * 32 + csw];
#pragma unroll
        for (int j = 0; j < 4; j++)
            b[j] = *(const bf16x8*)&Bs[cur][(wn * 64 + j * 16 + l15) * 32 + csw];
#pragma unroll
        for (int i = 0; i < 4; i++)
#pragma unroll
            for (int j = 0; j < 4; j++) acc[i][j] = MFMA(a[i], b[j], acc[i][j]);
        __syncthreads();
        cur ^= 1;
    }
#pragma unroll
    for (int j = 0; j < 4; j++) {
        int n = n0 + wn * 64 + j * 16 + l15;
        float bj = bias[n];
#pragma unroll
        for (int i = 0; i < 4; i++) {
#pragma unroll
            for (int v = 0; v < 4; v++) {
                int r = r0 + wm * 64 + i * 16 + quad * 4 + v;
                float val = acc[i][j][v] + bj + resx[(size_t)r * 1024 + n];
                if (r < 4096)
                    o_lo[(size_t)r * 1024 + n] = val;
                else
                    o_hi[(size_t)(r - 4096) * 1024 + n] = val;
            }
        }
    }
}

// --- colsum[bh][t] = sum_s exp(masked score) ; MFMA 64x64 tiles ------------
// Measured-best body + XCD remap (16 same-by blocks share qb panel).
__global__ __launch_bounds__(256) void colstats_mfma(
    const ushort_t* __restrict__ qb, const ushort_t* __restrict__ kb,
    const float* __restrict__ mask, int moff, float* __restrict__ colsum) {
    __shared__ ushort_t Ks[4096] __attribute__((aligned(16)));  // [2][64][32]
    __shared__ ushort_t Qs[4096] __attribute__((aligned(16)));
    __shared__ float mk[64], mq[64], red[4][64];
    int tid = threadIdx.x, w = tid >> 6, lane = tid & 63;
    int quad = lane >> 4, l15 = lane & 15;
    int csw = (quad ^ ((l15 >> 1) & 3)) * 8;
    int wg = xcd_remap();
    int by = wg / gridDim.x;
    int t0 = (wg % gridDim.x) * 64;
    size_t qoff = (size_t)by * 65536;
    int coff = by * 1024;
    int mb = moff + (by >> 4) * 1024;
#pragma unroll
    for (int ii = 0; ii < 2; ii++) {
        int qq = w * 2 + ii, half = qq >> 2, sub = qq & 3;
        int li = sub * 64 + lane, row = li >> 2, seg = li & 3;
        int sk = seg ^ ((row >> 1) & 3);
        GLDS(kb + qoff + (size_t)(t0 + row) * 64 + half * 32 + sk * 8,
             &Ks[half * 2048 + sub * 512]);
    }
    if (tid < 64) mk[tid] = mask[mb + t0 + tid];
    __syncthreads();
    // hoist K fragments (loop-invariant) into registers
    bf16x8 kf0[4], kf1[4];
#pragma unroll
    for (int j = 0; j < 4; j++) {
        kf0[j] = *(const bf16x8*)&Ks[(j * 16 + l15) * 32 + csw];
        kf1[j] = *(const bf16x8*)&Ks[2048 + (j * 16 + l15) * 32 + csw];
    }
    float amk[4];
#pragma unroll
    for (int j = 0; j < 4; j++) amk[j] = (mk[j * 16 + l15] > 0.f) ? 0.f : MNEG;
    float colacc[4] = {0.f, 0.f, 0.f, 0.f};
    for (int s0 = 0; s0 < 1024; s0 += 64) {
        __syncthreads();
#pragma unroll
        for (int ii = 0; ii < 2; ii++) {
            int qq = w * 2 + ii, half = qq >> 2, sub = qq & 3;
            int li = sub * 64 + lane, row = li >> 2, seg = li & 3;
            int sk = seg ^ ((row >> 1) & 3);
            GLDS(qb + qoff + (size_t)(s0 + row) * 64 + half * 32 + sk * 8,
                 &Qs[half * 2048 + sub * 512]);
        }
        if (tid < 64) mq[tid] = mask[mb + s0 + tid];
        __syncthreads();
        float amq[4];
#pragma unroll
        for (int v = 0; v < 4; v++)
            amq[v] = (mq[w * 16 + quad * 4 + v] > 0.f) ? 0.f : MNEG;
        bf16x8 a0 = *(const bf16x8*)&Qs[(w * 16 + l15) * 32 + csw];
        bf16x8 a1 = *(const bf16x8*)&Qs[2048 + (w * 16 + l15) * 32 + csw];
#pragma unroll
        for (int j = 0; j < 4; j++) {
            f32x4 sc = (f32x4){0.f, 0.f, 0.f, 0.f};
            sc = MFMA(a0, kf0[j], sc);
            sc = MFMA(a1, kf1[j], sc);
#pragma unroll
            for (int v = 0; v < 4; v++)
                colacc[j] += EXP2(sc[v] + amq[v] + amk[j]);
        }
    }
#pragma unroll
    for (int j = 0; j < 4; j++) {
        float vv = colacc[j];
        vv += __shfl_down(vv, 32);
        vv += __shfl_down(vv, 16);
        if (quad == 0) red[w][j * 16 + l15] = vv;
    }
    __syncthreads();
    if (tid < 64)
        colsum[coff + t0 + tid] = red[0][tid] + red[1][tid] + red[2][tid] + red[3][tid];
}

// --- double softmax + PV (MFMA); heads bf16, single base -------------------
// Measured-best body (separate __shared__ arrays, QE alias, GLDS staging).
#define ESTR 72
__global__ __launch_bounds__(256) void pv_mfma(
    const ushort_t* __restrict__ qb, const ushort_t* __restrict__ kb,
    const ushort_t* __restrict__ vtb, const float* __restrict__ mask, int moff,
    const float* __restrict__ colsum, ushort_t* __restrict__ H, int hbase) {
    __shared__ ushort_t Ks[4096] __attribute__((aligned(16)));
    __shared__ ushort_t Vt[4096] __attribute__((aligned(16)));  // [2][64dk][32t]
    __shared__ ushort_t QE[64 * ESTR] __attribute__((aligned(16)));
    __shared__ float mk[64], mq[64], ics[64];
    int tid = threadIdx.x, w = tid >> 6, lane = tid & 63;
    int quad = lane >> 4, l15 = lane & 15;
    int csw = (quad ^ ((l15 >> 1) & 3)) * 8;
    int wg = xcd_remap();
    int by = wg / gridDim.x;
    int s0 = (wg % gridDim.x) * 64;
    size_t qoff = (size_t)by * 65536;
    int coff = by * 1024;
    int mb = moff + (by >> 4) * 1024;
    int h = by & 15;
#pragma unroll
    for (int ii = 0; ii < 2; ii++) {
        int qq = w * 2 + ii, half = qq >> 2, sub = qq & 3;
        int li = sub * 64 + lane, row = li >> 2, seg = li & 3;
        int sk = seg ^ ((row >> 1) & 3);
        GLDS(qb + qoff + (size_t)(s0 + row) * 64 + half * 32 + sk * 8,
             &QE[half * 2048 + sub * 512]);
    }
    if (tid < 64) mq[tid] = mask[mb + s0 + tid];
    __syncthreads();
    // hoist Q fragments (loop-invariant); QE's Q contents dead after this
    bf16x8 a0 = *(const bf16x8*)&QE[(w * 16 + l15) * 32 + csw];
    bf16x8 a1 = *(const bf16x8*)&QE[2048 + (w * 16 + l15) * 32 + csw];
    float amq[4];
#pragma unroll
    for (int v = 0; v < 4; v++)
        amq[v] = (mq[w * 16 + quad * 4 + v] > 0.f) ? 0.f : MNEG;
    bf16x8 ones;
#pragma unroll
    for (int e = 0; e < 8; e++) ones[e] = (__bf16)1.0f;
    f32x4 acc_o[4], acc_rs = (f32x4){0.f, 0.f, 0.f, 0.f};
#pragma unroll
    for (int j = 0; j < 4; j++) acc_o[j] = (f32x4){0.f, 0.f, 0.f, 0.f};
    for (int t0 = 0; t0 < 1024; t0 += 64) {
        __syncthreads();
#pragma unroll
        for (int ii = 0; ii < 2; ii++) {
            int qq = w * 2 + ii, half = qq >> 2, sub = qq & 3;
            int li = sub * 64 + lane, row = li >> 2, seg = li & 3;
            int sk = seg ^ ((row >> 1) & 3);
            GLDS(kb + qoff + (size_t)(t0 + row) * 64 + half * 32 + sk * 8,
                 &Ks[half * 2048 + sub * 512]);
            GLDS(vtb + qoff + (size_t)row * 1024 + t0 + half * 32 + sk * 8,
                 &Vt[half * 2048 + sub * 512]);
        }
        if (tid < 64) {
            mk[tid] = mask[mb + t0 + tid];
            float cs = colsum[coff + t0 + tid];
            ics[tid] = (cs > 0.f) ? LOG2E / cs : 0.f;
        }
        __syncthreads();
#pragma unroll
        for (int j = 0; j < 4; j++) {
            bf16x8 b0 = *(const bf16x8*)&Ks[(j * 16 + l15) * 32 + csw];
            bf16x8 b1 = *(const bf16x8*)&Ks[2048 + (j * 16 + l15) * 32 + csw];
            f32x4 sc = (f32x4){0.f, 0.f, 0.f, 0.f};
            sc = MFMA(a0, b0, sc);
            sc = MFMA(a1, b1, sc);
            int tcol = j * 16 + l15;
            float icv = ics[tcol];
            float aj = (mk[tcol] > 0.f) ? 0.f : MNEG;
#pragma unroll
            for (int v = 0; v < 4; v++) {
                float e1 = EXP2(sc[v]);                       // exp(score/8)
                float e2 = EXP2(fmaf(e1, icv, amq[v] + aj));  // exp(attn1) or 0
                int sl = w * 16 + quad * 4 + v;
                QE[sl * ESTR + tcol] = (ushort_t)(__float_as_uint(e2) >> 16);
            }
        }
        // PV: each wave reads only its own 16-row E strip (same-wave LDS order)
        bf16x8 ea0 = *(const bf16x8*)&QE[(w * 16 + l15) * ESTR + quad * 8];
        bf16x8 ea1 = *(const bf16x8*)&QE[(w * 16 + l15) * ESTR + 32 + quad * 8];
#pragma unroll
        for (int j = 0; j < 4; j++) {
            bf16x8 b0 = *(const bf16x8*)&Vt[(j * 16 + l15) * 32 + csw];
            bf16x8 b1 = *(const bf16x8*)&Vt[2048 + (j * 16 + l15) * 32 + csw];
            acc_o[j] = MFMA(ea0, b0, acc_o[j]);
            acc_o[j] = MFMA(ea1, b1, acc_o[j]);
        }
        acc_rs = MFMA(ea0, ones, acc_rs);
        acc_rs = MFMA(ea1, ones, acc_rs);
    }
#pragma unroll
    for (int v = 0; v < 4; v++) {
        int sl = w * 16 + quad * 4 + v;
        int hr = hbase + (by >> 4) * 1024 + s0 + sl;
        ushort_t* hp = H + (size_t)hr * 1024;
        float inv = 1.0f / fmaxf(acc_rs[v], 1e-30f);
#pragma unroll
        for (int j = 0; j < 4; j++)
            hp[h * 64 + j * 16 + l15] = f2bf(acc_o[j][v] * inv);
    }
}

extern "C" void kernel_launch(void* const* d_in, const int* in_sizes, int n_in,
                              void* d_out, int out_size, void* d_ws, size_t ws_size,
                              hipStream_t stream) {
    const float* x     = (const float*)d_in[0];
    const float* mask  = (const float*)d_in[1];
    const float* wq    = (const float*)d_in[2];
    const float* bq    = (const float*)d_in[3];
    const float* wk    = (const float*)d_in[4];
    const float* bk    = (const float*)d_in[5];
    const float* wv    = (const float*)d_in[6];
    const float* bv    = (const float*)d_in[7];
    const float* w_out = (const float*)d_in[8];
    const float* b_out = (const float*)d_in[9];
    float* outp = (float*)d_out;

    const size_t MB = 1024 * 1024;
    ushort_t* xn = (ushort_t*)d_out;             // bytes [0,16MB), dead after qkv
    ushort_t* H  = (ushort_t*)d_out + 8 * MB;    // heads bf16, bytes [16MB,32MB)
    char* ws = (char*)d_ws;

    if (ws_size >= 58 * MB) {
        ushort_t* qb  = (ushort_t*)ws;             // 16 MB (dead after pv)
        ushort_t* kb  = (ushort_t*)(ws + 16 * MB); // 16 MB (dead after pv)
        ushort_t* vtb = (ushort_t*)(ws + 32 * MB); // 16 MB
        float* csum   = (float*)(ws + 48 * MB);    // 512 KB
        ushort_t* wqb = (ushort_t*)(ws + 49 * MB);
        ushort_t* wkb = (ushort_t*)(ws + 51 * MB);
        ushort_t* wvb = (ushort_t*)(ws + 53 * MB);
        ushort_t* wob = (ushort_t*)(ws + 55 * MB);
        float* ohi    = (float*)ws;                // 16 MB: out rows [4096,8192)
        prep<<<dim3(12288), 256, 0, stream>>>(x, xn, wq, wk, wv, w_out,
                                              wqb, wkb, wvb, wob);
        gemm_mfma<0, 0><<<dim3(8, 64, 3), 256, 0, stream>>>(
            xn, wqb, wkb, wvb, bq, bk, bv, qb, kb, vtb, nullptr, nullptr, 1,
            0, 0, 0);
        colstats_mfma<<<dim3(16, 128), 256, 0, stream>>>(qb, kb, mask, 0, csum);
        pv_mfma<<<dim3(16, 128), 256, 0, stream>>>(qb, kb, vtb, mask, 0, csum, H, 0);
        // merged out-proj (standalone kernel): rows<4096 -> d_out directly
        // (xn dead, no H overlap); rows>=4096 -> ohi (qb dead), then 16MB
        // copy over H.
        gemm_out<<<dim3(8, 64), 256, 0, stream>>>(H, wob, b_out, (float*)d_out,
                                                  ohi, x);
        hipMemcpyAsync((char*)d_out + 16 * MB, ws, 16 * MB,
                       hipMemcpyDeviceToDevice, stream);
    } else {
        // compact path: <= 6.07 MB ws; in-place cascade out-proj
        ushort_t* qb  = (ushort_t*)ws;            // 2 MB
        ushort_t* kb  = (ushort_t*)(ws + 2 * MB); // 2 MB
        ushort_t* vtb = (ushort_t*)(ws + 4 * MB); // 2 MB
        float* csum   = (float*)(ws + 6 * MB);    // 64 KB
        ushort_t* hcopy = (ushort_t*)ws;          // 256KB tail copy (qb dead)
        const int casc[6][2] = {{0, 32},   {4096, 16}, {6144, 8},
                                {7168, 4}, {7680, 2},  {7936, 1}};
        ln_kernel<<<dim3(8192), 256, 0, stream>>>(x, xn);
        for (int g = 0; g < 8; g++) {
            gemm_mfma<1, 0><<<dim3(8, 8, 3), 256, 0, stream>>>(
                xn + (size_t)g * MB, wq, wk, wv, bq, bk, bv, qb, kb, vtb,
                nullptr, nullptr, 0, 0, 0, 0);
            colstats_mfma<<<dim3(16, 16), 256, 0, stream>>>(qb, kb, mask,
                                                            g * 1024, csum);
            pv_mfma<<<dim3(16, 16), 256, 0, stream>>>(qb, kb, vtb, mask,
                                                      g * 1024, csum, H, g * 1024);
        }
        tailcopy<<<dim3(64), 256, 0, stream>>>((const us8*)(H + (size_t)8064 * 1024),
                                               (us8*)hcopy);
        for (int i = 0; i < 6; i++)
            gemm_mfma<1, 1><<<dim3(8, casc[i][1]), 256, 0, stream>>>(
                H, w_out, w_out, w_out, b_out, b_out, b_out, nullptr, nullptr,
                nullptr, outp, x, 0, casc[i][0], 0, 0);
        gemm_mfma<1, 1><<<dim3(8, 1), 256, 0, stream>>>(
            hcopy, w_out, w_out, w_out, b_out, b_out, b_out, nullptr, nullptr,
            nullptr, outp, x, 0, 8064, 8064, 0);
    }
}

// Round 17
// 304.721 us; speedup vs baseline: 1.0871x; 1.0497x over previous
//
#include <hip/hip_runtime.h>

// B=8, S=1024, H=16, DK=64, D=1024. Inputs/outputs fp32. Internal bf16 MFMA.
// Q pre-scaled by log2(e)/8; exps raw v_exp_f32; masking additive -1e9.
// GLDS LDS tiles XOR-swizzled (chunk ^ ((row>>1)&3)); reads use
// quad ^ ((l15>>1)&3) -> conflicts 8-way -> 2-way (free).
// FINAL = byte-exact R10 source, the only text measured in the 306-310us
// band (R10 306.1 / R12 307.4 / R13 310.1; session start 354.5, -14%).
// Ledger IN: gemm 2-phase dbuf prefetch; XCD remap (m204 bijective) on all
// MFMA kernels (gemm FETCH 200->85MB); V-epilogue LDS transpose (qkv
// 122->~75us); pv separate-__shared__ arrays + QE alias (26.6KB LDS,
// 6 blocks/CU); prep merge (ln + 4x wconv); merged out-proj (one 8x64
// launch, worth ~20us vs split 2x 8x32); 16MB memcpy.
// Known risk: <0,0> codegen is BIMODAL across compiles (3/5 good at ~75us,
// 2/5 bad at ~90us/VGPR92 -- template-sibling kernarg perturbation).
// Standalone-gemm_out (R16) and split-out-proj (R15) alternatives both
// measured WORSE (319.9 / 331.3).
// Measured NULL: attn XCD remap on time (FETCH -6x, latency-bound), occ
// 4->6 blocks (+3%), QBLK/TBLK=128, setprio x3, depth-1/2 gemm pipelining.
// Measured NEGATIVE: counted-vmcnt asm clobbers (VALU 14->38%), one-pool
// LDS (alias loss -> DS serialization), T14 reg-staging (~16% tax vs
// gload_lds). pv 77us floor = double-EXP2 serial chain; qkv ~75us = 687TF
// = 2-phase/128-tile ceiling. Beyond this structure: T12 swapped-QK
// in-register softmax; 8-phase 256-tile gemm port.

typedef unsigned short ushort_t;
typedef unsigned short us4 __attribute__((ext_vector_type(4)));
typedef unsigned short us8 __attribute__((ext_vector_type(8)));
typedef __bf16 bf16x8 __attribute__((ext_vector_type(8)));
typedef float f32x4 __attribute__((ext_vector_type(4)));

#define QSCALE 0.18033688011112042f  // log2(e)/8
#define LOG2E 1.4426950408889634f
#define MNEG (-1.0e9f)
#define EXP2(x) __builtin_amdgcn_exp2f(x)

__device__ __forceinline__ ushort_t f2bf(float f) {
    unsigned int u = __float_as_uint(f);
    return (ushort_t)((u + 0x7fffu + ((u >> 16) & 1u)) >> 16);  // RTNE
}

// bijective XCD chunk remap (m204): blocks sharing input panels get
// consecutive work ids -> same XCD -> panel stays in that XCD's L2.
__device__ __forceinline__ int xcd_remap() {
    int nwg = gridDim.x * gridDim.y * gridDim.z;
    int o = blockIdx.x + gridDim.x * (blockIdx.y + gridDim.y * blockIdx.z);
    int q = nwg >> 3, r = nwg & 7;
    int xcd = o & 7, i = o >> 3;
    return (xcd < r ? xcd * (q + 1) : r * (q + 1) + (xcd - r) * q) + i;
}

// async global->LDS, 16B/lane; LDS dst = wave-uniform base + lane*16
#define GLDS(gp, lp)                                                        \
    __builtin_amdgcn_global_load_lds(                                       \
        (const __attribute__((address_space(1))) unsigned int*)(gp),        \
        (__attribute__((address_space(3))) unsigned int*)(lp), 16, 0, 0)

#define MFMA(a, b, c) __builtin_amdgcn_mfma_f32_16x16x32_bf16((a), (b), (c), 0, 0, 0)

// ---------------- LayerNorm: x fp32 [8192][1024] -> xn bf16 ----------------
__global__ __launch_bounds__(256) void ln_kernel(const float* __restrict__ x,
                                                 ushort_t* __restrict__ xn) {
    int row = blockIdx.x, tid = threadIdx.x;
    float4 v = ((const float4*)(x + (size_t)row * 1024))[tid];
    float s = v.x + v.y + v.z + v.w;
    __shared__ float red[8];
    for (int o = 32; o > 0; o >>= 1) s += __shfl_down(s, o);
    int wave = tid >> 6, lane = tid & 63;
    if (lane == 0) red[wave] = s;
    __syncthreads();
    float mu = (red[0] + red[1] + red[2] + red[3]) * (1.0f / 1024.0f);
    float d0 = v.x - mu, d1 = v.y - mu, d2 = v.z - mu, d3 = v.w - mu;
    float q = d0 * d0 + d1 * d1 + d2 * d2 + d3 * d3;
    for (int o = 32; o > 0; o >>= 1) q += __shfl_down(q, o);
    if (lane == 0) red[wave + 4] = q;
    __syncthreads();
    float var = (red[4] + red[5] + red[6] + red[7]) * (1.0f / 1024.0f);
    float rs = rsqrtf(var + 1e-5f);
    us4 ov;
    ov[0] = f2bf(d0 * rs); ov[1] = f2bf(d1 * rs);
    ov[2] = f2bf(d2 * rs); ov[3] = f2bf(d3 * rs);
    ((us4*)(xn + (size_t)row * 1024))[tid] = ov;
}

// --- prep: LayerNorm (blocks [0,8192)) + 4x weight fp32->bf16 convert ------
// (blocks [8192,12288)) fused into one launch; branch is block-uniform.
__global__ __launch_bounds__(256) void prep(
    const float* __restrict__ x, ushort_t* __restrict__ xn,
    const float* __restrict__ s0, const float* __restrict__ s1,
    const float* __restrict__ s2, const float* __restrict__ s3,
    ushort_t* __restrict__ d0, ushort_t* __restrict__ d1,
    ushort_t* __restrict__ d2, ushort_t* __restrict__ d3) {
    int b = blockIdx.x, tid = threadIdx.x;
    if (b < 8192) {
        int row = b;
        float4 v = ((const float4*)(x + (size_t)row * 1024))[tid];
        float s = v.x + v.y + v.z + v.w;
        __shared__ float red[8];
        for (int o = 32; o > 0; o >>= 1) s += __shfl_down(s, o);
        int wave = tid >> 6, lane = tid & 63;
        if (lane == 0) red[wave] = s;
        __syncthreads();
        float mu = (red[0] + red[1] + red[2] + red[3]) * (1.0f / 1024.0f);
        float e0 = v.x - mu, e1 = v.y - mu, e2 = v.z - mu, e3 = v.w - mu;
        float q = e0 * e0 + e1 * e1 + e2 * e2 + e3 * e3;
        for (int o = 32; o > 0; o >>= 1) q += __shfl_down(q, o);
        if (lane == 0) red[wave + 4] = q;
        __syncthreads();
        float var = (red[4] + red[5] + red[6] + red[7]) * (1.0f / 1024.0f);
        float rs = rsqrtf(var + 1e-5f);
        us4 ov;
        ov[0] = f2bf(e0 * rs); ov[1] = f2bf(e1 * rs);
        ov[2] = f2bf(e2 * rs); ov[3] = f2bf(e3 * rs);
        ((us4*)(xn + (size_t)row * 1024))[tid] = ov;
    } else {
        int i = b - 8192;  // [0,4096): 4 tensors x 1024 blocks
        int sel = i >> 10, blk = i & 1023;
        const float* s = (sel == 0) ? s0 : (sel == 1) ? s1 : (sel == 2) ? s2 : s3;
        ushort_t* d = (sel == 0) ? d0 : (sel == 1) ? d1 : (sel == 2) ? d2 : d3;
        size_t idx = ((size_t)blk * 256 + tid) * 4;
        float4 f = *(const float4*)(s + idx);
        us4 o;
        o[0] = f2bf(f.x); o[1] = f2bf(f.y); o[2] = f2bf(f.z); o[3] = f2bf(f.w);
        *(us4*)(d + idx) = o;
    }
}

// ------------- bf16 tail copy: 128 rows (compact path only) ----------------
__global__ __launch_bounds__(256) void tailcopy(const us8* __restrict__ src,
                                                us8* __restrict__ dst) {
    size_t i = (size_t)blockIdx.x * 256 + threadIdx.x;  // 16384 us8
    dst[i] = src[i];
}

// --------- MFMA bt-GEMM: C[r][n] = sum_k A[r][k] * B[n][k] + bias[n] -------
// BMODE 0: B bf16 (async staged); 1: B fp32 (VALU convert staged)
// OMODE 0: qkv epilogue (q/k direct bf16 stores; v via LDS transpose)
// OMODE 1: fp32 out + residual. If ovt!=nullptr: split mode (rows<osub ->
// ofp@r, rows>=osub -> (float*)ovt@(r-osub)); else legacy ofp@(r-osub).
template <int BMODE, int OMODE>
__global__ __launch_bounds__(256) void gemm_mfma(
    const ushort_t* __restrict__ A, const void* __restrict__ Bq,
    const void* __restrict__ Bk, const void* __restrict__ Bv,
    const float* __restrict__ biasq, const float* __restrict__ biask,
    const float* __restrict__ biasv, ushort_t* __restrict__ oq,
    ushort_t* __restrict__ ok, ushort_t* __restrict__ ovt,
    float* __restrict__ ofp, const float* __restrict__ resx, int batched,
    int r0base, int aoff, int osub) {
    // 2x(A)+2x(B) staging buffers; contiguous so the epilogue can reuse all
    // 32KB as a 128x128 bf16 transpose scratch.
    __shared__ ushort_t SMEM[4][128 * 32] __attribute__((aligned(16)));
#define AS_(b) (SMEM[(b)])
#define BS_(b) (SMEM[2 + (b)])
    int tid = threadIdx.x, w = tid >> 6, lane = tid & 63;
    int quad = lane >> 4, l15 = lane & 15;
    int wm = w & 1, wn = w >> 1;
    int csw = (quad ^ ((l15 >> 1) & 3)) * 8;  // swizzled chunk offset
    // panel-major decomposition of XCD-chunked work id: y outer, (z,x) inner
    int wg = xcd_remap();
    int gxz = gridDim.x * gridDim.z;
    int wy = wg / gxz, wt = wg % gxz;
    int n0 = (wt % gridDim.x) * 128;
    int r0 = r0base + wy * 128;
    int wsel = wt / gridDim.x;
    const void* Bp = (wsel == 0) ? Bq : (wsel == 1) ? Bk : Bv;
    const float* biasp = (wsel == 0) ? biasq : (wsel == 1) ? biask : biasv;
    const float qscale = (OMODE == 0 && wsel == 0) ? QSCALE : 1.0f;

    auto stage = [&](int buf, int k0) {
#pragma unroll
        for (int ii = 0; ii < 2; ii++) {  // A tile 128x32 (8KB)
            int li = (w * 2 + ii) * 64 + lane;
            int row = li >> 2, kc = li & 3;
            int sk = kc ^ ((row >> 1) & 3);
            GLDS(A + (size_t)(r0 + row - aoff) * 1024 + k0 + sk * 8,
                 &AS_(buf)[(w * 2 + ii) * 512]);
        }
        if (BMODE == 0) {
#pragma unroll
            for (int ii = 0; ii < 2; ii++) {
                int li = (w * 2 + ii) * 64 + lane;
                int row = li >> 2, kc = li & 3;
                int sk = kc ^ ((row >> 1) & 3);
                GLDS((const ushort_t*)Bp + (size_t)(n0 + row) * 1024 + k0 + sk * 8,
                     &BS_(buf)[(w * 2 + ii) * 512]);
            }
        } else {
            int row = tid >> 1, half = tid & 1;
            int sw = (row >> 1) & 3;
            const float* gb =
                (const float*)Bp + (size_t)(n0 + row) * 1024 + k0 + half * 16;
            float4 f0 = *(const float4*)gb;
            float4 f1 = *(const float4*)(gb + 4);
            float4 f2 = *(const float4*)(gb + 8);
            float4 f3 = *(const float4*)(gb + 12);
            us8 p0, p1;
            p0[0] = f2bf(f0.x); p0[1] = f2bf(f0.y); p0[2] = f2bf(f0.z); p0[3] = f2bf(f0.w);
            p0[4] = f2bf(f1.x); p0[5] = f2bf(f1.y); p0[6] = f2bf(f1.z); p0[7] = f2bf(f1.w);
            p1[0] = f2bf(f2.x); p1[1] = f2bf(f2.y); p1[2] = f2bf(f2.z); p1[3] = f2bf(f2.w);
            p1[4] = f2bf(f3.x); p1[5] = f2bf(f3.y); p1[6] = f2bf(f3.z); p1[7] = f2bf(f3.w);
            *(us8*)&BS_(buf)[row * 32 + ((half * 2) ^ sw) * 8] = p0;
            *(us8*)&BS_(buf)[row * 32 + ((half * 2 + 1) ^ sw) * 8] = p1;
        }
    };

    f32x4 acc[4][4];
    stage(0, 0);  // prologue: tile 0 in flight while acc zeroed
#pragma unroll
    for (int i = 0; i < 4; i++)
#pragma unroll
        for (int j = 0; j < 4; j++) acc[i][j] = (f32x4){0.f, 0.f, 0.f, 0.f};
    __syncthreads();

    int cur = 0;
    for (int k0 = 0; k0 < 1024; k0 += 32) {
        if (k0 + 32 < 1024) stage(cur ^ 1, k0 + 32);  // prefetch next tile
        bf16x8 a[4], b[4];
#pragma unroll
        for (int i = 0; i < 4; i++)
            a[i] = *(const bf16x8*)&AS_(cur)[(wm * 64 + i * 16 + l15) * 32 + csw];
#pragma unroll
        for (int j = 0; j < 4; j++)
            b[j] = *(const bf16x8*)&BS_(cur)[(wn * 64 + j * 16 + l15) * 32 + csw];
#pragma unroll
        for (int i = 0; i < 4; i++)
#pragma unroll
            for (int j = 0; j < 4; j++) acc[i][j] = MFMA(a[i], b[j], acc[i][j]);
        __syncthreads();  // drains this iter's prefetch; next tile ready
        cur ^= 1;
    }
    // epilogue; C layout: col=l15, row=quad*4+v
    if (OMODE == 0 && wsel == 2) {
        // V: transpose 128x128 tile through LDS -> 16B-contiguous global
        // stores (was 2B stores at 2KB stride). XOR swizzle (n&15)<<3 keeps
        // us8 chunks aligned and spreads banks.
        ushort_t* TP = &SMEM[0][0];
#pragma unroll
        for (int j = 0; j < 4; j++) {
            int nl = wn * 64 + j * 16 + l15;
            float bj = biasp[n0 + nl];
#pragma unroll
            for (int i = 0; i < 4; i++)
#pragma unroll
                for (int v = 0; v < 4; v++) {
                    int rl = wm * 64 + i * 16 + quad * 4 + v;
                    TP[nl * 128 + (rl ^ ((nl & 15) << 3))] =
                        f2bf(acc[i][j][v] + bj);
                }
        }
        __syncthreads();
        int row = tid >> 1, half = tid & 1;  // row = local n (out row)
        int n = n0 + row, hh = n >> 6, kk = n & 63;
        int bb = batched ? (r0 >> 10) : 0;
        int sbase = (r0 & 1023) + half * 64;
        ushort_t* gp = ovt + ((size_t)(bb * 16 + hh) * 64 + kk) * 1024 + sbase;
#pragma unroll
        for (int c = 0; c < 8; c++) {
            us8 vv = *(const us8*)&TP[row * 128 +
                                      ((half * 64 + c * 8) ^ ((row & 15) << 3))];
            *(us8*)(gp + c * 8) = vv;
        }
    } else {
#pragma unroll
        for (int j = 0; j < 4; j++) {
            int n = n0 + wn * 64 + j * 16 + l15;
            float bj = biasp[n];
            if (OMODE == 0) {
                int h = n >> 6, kk = n & 63;
#pragma unroll
                for (int i = 0; i < 4; i++) {
#pragma unroll
                    for (int v = 0; v < 4; v++) {
                        int r = r0 + wm * 64 + i * 16 + quad * 4 + v;
                        int bb = batched ? (r >> 10) : 0;
                        int s = r & 1023;
                        ushort_t val = f2bf((acc[i][j][v] + bj) * qscale);
                        ushort_t* op = (wsel == 0) ? oq : ok;
                        op[((size_t)(bb * 16 + h) * 1024 + s) * 64 + kk] = val;
                    }
                }
            } else {
#pragma unroll
                for (int i = 0; i < 4; i++) {
#pragma unroll
                    for (int v = 0; v < 4; v++) {
                        int r = r0 + wm * 64 + i * 16 + quad * 4 + v;
                        float* ob;
                        int ro;
                        if (ovt != nullptr) {  // merged out-proj routing
                            ob = (r < osub) ? ofp : (float*)ovt;
                            ro = (r < osub) ? r : r - osub;
                        } else {
                            ob = ofp;
                            ro = r - osub;
                        }
                        ob[(size_t)ro * 1024 + n] =
                            acc[i][j][v] + bj + resx[(size_t)r * 1024 + n];
                    }
                }
            }
        }
    }
#undef AS_
#undef BS_
}

// --- colsum[bh][t] = sum_s exp(masked score) ; MFMA 64x64 tiles ------------
// Measured-best body + XCD remap (16 same-by blocks share qb panel).
__global__ __launch_bounds__(256) void colstats_mfma(
    const ushort_t* __restrict__ qb, const ushort_t* __restrict__ kb,
    const float* __restrict__ mask, int moff, float* __restrict__ colsum) {
    __shared__ ushort_t Ks[4096] __attribute__((aligned(16)));  // [2][64][32]
    __shared__ ushort_t Qs[4096] __attribute__((aligned(16)));
    __shared__ float mk[64], mq[64], red[4][64];
    int tid = threadIdx.x, w = tid >> 6, lane = tid & 63;
    int quad = lane >> 4, l15 = lane & 15;
    int csw = (quad ^ ((l15 >> 1) & 3)) * 8;
    int wg = xcd_remap();
    int by = wg / gridDim.x;
    int t0 = (wg % gridDim.x) * 64;
    size_t qoff = (size_t)by * 65536;
    int coff = by * 1024;
    int mb = moff + (by >> 4) * 1024;
#pragma unroll
    for (int ii = 0; ii < 2; ii++) {
        int qq = w * 2 + ii, half = qq >> 2, sub = qq & 3;
        int li = sub * 64 + lane, row = li >> 2, seg = li & 3;
        int sk = seg ^ ((row >> 1) & 3);
        GLDS(kb + qoff + (size_t)(t0 + row) * 64 + half * 32 + sk * 8,
             &Ks[half * 2048 + sub * 512]);
    }
    if (tid < 64) mk[tid] = mask[mb + t0 + tid];
    __syncthreads();
    // hoist K fragments (loop-invariant) into registers
    bf16x8 kf0[4], kf1[4];
#pragma unroll
    for (int j = 0; j < 4; j++) {
        kf0[j] = *(const bf16x8*)&Ks[(j * 16 + l15) * 32 + csw];
        kf1[j] = *(const bf16x8*)&Ks[2048 + (j * 16 + l15) * 32 + csw];
    }
    float amk[4];
#pragma unroll
    for (int j = 0; j < 4; j++) amk[j] = (mk[j * 16 + l15] > 0.f) ? 0.f : MNEG;
    float colacc[4] = {0.f, 0.f, 0.f, 0.f};
    for (int s0 = 0; s0 < 1024; s0 += 64) {
        __syncthreads();
#pragma unroll
        for (int ii = 0; ii < 2; ii++) {
            int qq = w * 2 + ii, half = qq >> 2, sub = qq & 3;
            int li = sub * 64 + lane, row = li >> 2, seg = li & 3;
            int sk = seg ^ ((row >> 1) & 3);
            GLDS(qb + qoff + (size_t)(s0 + row) * 64 + half * 32 + sk * 8,
                 &Qs[half * 2048 + sub * 512]);
        }
        if (tid < 64) mq[tid] = mask[mb + s0 + tid];
        __syncthreads();
        float amq[4];
#pragma unroll
        for (int v = 0; v < 4; v++)
            amq[v] = (mq[w * 16 + quad * 4 + v] > 0.f) ? 0.f : MNEG;
        bf16x8 a0 = *(const bf16x8*)&Qs[(w * 16 + l15) * 32 + csw];
        bf16x8 a1 = *(const bf16x8*)&Qs[2048 + (w * 16 + l15) * 32 + csw];
#pragma unroll
        for (int j = 0; j < 4; j++) {
            f32x4 sc = (f32x4){0.f, 0.f, 0.f, 0.f};
            sc = MFMA(a0, kf0[j], sc);
            sc = MFMA(a1, kf1[j], sc);
#pragma unroll
            for (int v = 0; v < 4; v++)
                colacc[j] += EXP2(sc[v] + amq[v] + amk[j]);
        }
    }
#pragma unroll
    for (int j = 0; j < 4; j++) {
        float vv = colacc[j];
        vv += __shfl_down(vv, 32);
        vv += __shfl_down(vv, 16);
        if (quad == 0) red[w][j * 16 + l15] = vv;
    }
    __syncthreads();
    if (tid < 64)
        colsum[coff + t0 + tid] = red[0][tid] + red[1][tid] + red[2][tid] + red[3][tid];
}

// --- double softmax + PV (MFMA); heads bf16, single base -------------------
// Measured-best body (separate __shared__ arrays, QE alias, GLDS staging).
#define ESTR 72
__global__ __launch_bounds__(256) void pv_mfma(
    const ushort_t* __restrict__ qb, const ushort_t* __restrict__ kb,
    const ushort_t* __restrict__ vtb, const float* __restrict__ mask, int moff,
    const float* __restrict__ colsum, ushort_t* __restrict__ H, int hbase) {
    __shared__ ushort_t Ks[4096] __attribute__((aligned(16)));
    __shared__ ushort_t Vt[4096] __attribute__((aligned(16)));  // [2][64dk][32t]
    __shared__ ushort_t QE[64 * ESTR] __attribute__((aligned(16)));
    __shared__ float mk[64], mq[64], ics[64];
    int tid = threadIdx.x, w = tid >> 6, lane = tid & 63;
    int quad = lane >> 4, l15 = lane & 15;
    int csw = (quad ^ ((l15 >> 1) & 3)) * 8;
    int wg = xcd_remap();
    int by = wg / gridDim.x;
    int s0 = (wg % gridDim.x) * 64;
    size_t qoff = (size_t)by * 65536;
    int coff = by * 1024;
    int mb = moff + (by >> 4) * 1024;
    int h = by & 15;
#pragma unroll
    for (int ii = 0; ii < 2; ii++) {
        int qq = w * 2 + ii, half = qq >> 2, sub = qq & 3;
        int li = sub * 64 + lane, row = li >> 2, seg = li & 3;
        int sk = seg ^ ((row >> 1) & 3);
        GLDS(qb + qoff + (size_t)(s0 + row) * 64 + half * 32 + sk * 8,
             &QE[half * 2048 + sub * 512]);
    }
    if (tid < 64) mq[tid] = mask[mb + s0 + tid];
    __syncthreads();
    // hoist Q fragments (loop-invariant); QE's Q contents dead after this
    bf16x8 a0 = *(const bf16x8*)&QE[(w * 16 + l15) * 32 + csw];
    bf16x8 a1 = *(const bf16x8*)&QE[2048 + (w * 16 + l15) * 32 + csw];
    float amq[4];
#pragma unroll
    for (int v = 0; v < 4; v++)
        amq[v] = (mq[w * 16 + quad * 4 + v] > 0.f) ? 0.f : MNEG;
    bf16x8 ones;
#pragma unroll
    for (int e = 0; e < 8; e++) ones[e] = (__bf16)1.0f;
    f32x4 acc_o[4], acc_rs = (f32x4){0.f, 0.f, 0.f, 0.f};
#pragma unroll
    for (int j = 0; j < 4; j++) acc_o[j] = (f32x4){0.f, 0.f, 0.f, 0.f};
    for (int t0 = 0; t0 < 1024; t0 += 64) {
        __syncthreads();
#pragma unroll
        for (int ii = 0; ii < 2; ii++) {
            int qq = w * 2 + ii, half = qq >> 2, sub = qq & 3;
            int li = sub * 64 + lane, row = li >> 2, seg = li & 3;
            int sk = seg ^ ((row >> 1) & 3);
            GLDS(kb + qoff + (size_t)(t0 + row) * 64 + half * 32 + sk * 8,
                 &Ks[half * 2048 + sub * 512]);
            GLDS(vtb + qoff + (size_t)row * 1024 + t0 + half * 32 + sk * 8,
                 &Vt[half * 2048 + sub * 512]);
        }
        if (tid < 64) {
            mk[tid] = mask[mb + t0 + tid];
            float cs = colsum[coff + t0 + tid];
            ics[tid] = (cs > 0.f) ? LOG2E / cs : 0.f;
        }
        __syncthreads();
#pragma unroll
        for (int j = 0; j < 4; j++) {
            bf16x8 b0 = *(const bf16x8*)&Ks[(j * 16 + l15) * 32 + csw];
            bf16x8 b1 = *(const bf16x8*)&Ks[2048 + (j * 16 + l15) * 32 + csw];
            f32x4 sc = (f32x4){0.f, 0.f, 0.f, 0.f};
            sc = MFMA(a0, b0, sc);
            sc = MFMA(a1, b1, sc);
            int tcol = j * 16 + l15;
            float icv = ics[tcol];
            float aj = (mk[tcol] > 0.f) ? 0.f : MNEG;
#pragma unroll
            for (int v = 0; v < 4; v++) {
                float e1 = EXP2(sc[v]);                       // exp(score/8)
                float e2 = EXP2(fmaf(e1, icv, amq[v] + aj));  // exp(attn1) or 0
                int sl = w * 16 + quad * 4 + v;
                QE[sl * ESTR + tcol] = (ushort_t)(__float_as_uint(e2) >> 16);
            }
        }
        // PV: each wave reads only its own 16-row E strip (same-wave LDS order)
        bf16x8 ea0 = *(const bf16x8*)&QE[(w * 16 + l15) * ESTR + quad * 8];
        bf16x8 ea1 = *(const bf16x8*)&QE[(w * 16 + l15) * ESTR + 32 + quad * 8];
#pragma unroll
        for (int j = 0; j < 4; j++) {
            bf16x8 b0 = *(const bf16x8*)&Vt[(j * 16 + l15) * 32 + csw];
            bf16x8 b1 = *(const bf16x8*)&Vt[2048 + (j * 16 + l15) * 32 + csw];
            acc_o[j] = MFMA(ea0, b0, acc_o[j]);
            acc_o[j] = MFMA(ea1, b1, acc_o[j]);
        }
        acc_rs = MFMA(ea0, ones, acc_rs);
        acc_rs = MFMA(ea1, ones, acc_rs);
    }
#pragma unroll
    for (int v = 0; v < 4; v++) {
        int sl = w * 16 + quad * 4 + v;
        int hr = hbase + (by >> 4) * 1024 + s0 + sl;
        ushort_t* hp = H + (size_t)hr * 1024;
        float inv = 1.0f / fmaxf(acc_rs[v], 1e-30f);
#pragma unroll
        for (int j = 0; j < 4; j++)
            hp[h * 64 + j * 16 + l15] = f2bf(acc_o[j][v] * inv);
    }
}

extern "C" void kernel_launch(void* const* d_in, const int* in_sizes, int n_in,
                              void* d_out, int out_size, void* d_ws, size_t ws_size,
                              hipStream_t stream) {
    const float* x     = (const float*)d_in[0];
    const float* mask  = (const float*)d_in[1];
    const float* wq    = (const float*)d_in[2];
    const float* bq    = (const float*)d_in[3];
    const float* wk    = (const float*)d_in[4];
    const float* bk    = (const float*)d_in[5];
    const float* wv    = (const float*)d_in[6];
    const float* bv    = (const float*)d_in[7];
    const float* w_out = (const float*)d_in[8];
    const float* b_out = (const float*)d_in[9];
    float* outp = (float*)d_out;

    const size_t MB = 1024 * 1024;
    ushort_t* xn = (ushort_t*)d_out;             // bytes [0,16MB), dead after qkv
    ushort_t* H  = (ushort_t*)d_out + 8 * MB;    // heads bf16, bytes [16MB,32MB)
    char* ws = (char*)d_ws;

    if (ws_size >= 58 * MB) {
        ushort_t* qb  = (ushort_t*)ws;             // 16 MB (dead after pv)
        ushort_t* kb  = (ushort_t*)(ws + 16 * MB); // 16 MB (dead after pv)
        ushort_t* vtb = (ushort_t*)(ws + 32 * MB); // 16 MB
        float* csum   = (float*)(ws + 48 * MB);    // 512 KB
        ushort_t* wqb = (ushort_t*)(ws + 49 * MB);
        ushort_t* wkb = (ushort_t*)(ws + 51 * MB);
        ushort_t* wvb = (ushort_t*)(ws + 53 * MB);
        ushort_t* wob = (ushort_t*)(ws + 55 * MB);
        float* ohi    = (float*)ws;                // 16 MB: out rows [4096,8192)
        prep<<<dim3(12288), 256, 0, stream>>>(x, xn, wq, wk, wv, w_out,
                                              wqb, wkb, wvb, wob);
        gemm_mfma<0, 0><<<dim3(8, 64, 3), 256, 0, stream>>>(
            xn, wqb, wkb, wvb, bq, bk, bv, qb, kb, vtb, nullptr, nullptr, 1,
            0, 0, 0);
        colstats_mfma<<<dim3(16, 128), 256, 0, stream>>>(qb, kb, mask, 0, csum);
        pv_mfma<<<dim3(16, 128), 256, 0, stream>>>(qb, kb, vtb, mask, 0, csum, H, 0);
        // merged out-proj (split mode via ovt/osub): rows<4096 -> d_out
        // directly (xn dead, no H overlap); rows>=4096 -> ohi (qb dead),
        // then 16MB copy over H.
        gemm_mfma<0, 1><<<dim3(8, 64), 256, 0, stream>>>(
            H, wob, wob, wob, b_out, b_out, b_out, nullptr, nullptr,
            (ushort_t*)ohi, (float*)d_out, x, 0, 0, 0, 4096);
        hipMemcpyAsync((char*)d_out + 16 * MB, ws, 16 * MB,
                       hipMemcpyDeviceToDevice, stream);
    } else {
        // compact path: <= 6.07 MB ws; in-place cascade out-proj
        ushort_t* qb  = (ushort_t*)ws;            // 2 MB
        ushort_t* kb  = (ushort_t*)(ws + 2 * MB); // 2 MB
        ushort_t* vtb = (ushort_t*)(ws + 4 * MB); // 2 MB
        float* csum   = (float*)(ws + 6 * MB);    // 64 KB
        ushort_t* hcopy = (ushort_t*)ws;          // 256KB tail copy (qb dead)
        const int casc[6][2] = {{0, 32},   {4096, 16}, {6144, 8},
                                {7168, 4}, {7680, 2},  {7936, 1}};
        ln_kernel<<<dim3(8192), 256, 0, stream>>>(x, xn);
        for (int g = 0; g < 8; g++) {
            gemm_mfma<1, 0><<<dim3(8, 8, 3), 256, 0, stream>>>(
                xn + (size_t)g * MB, wq, wk, wv, bq, bk, bv, qb, kb, vtb,
                nullptr, nullptr, 0, 0, 0, 0);
            colstats_mfma<<<dim3(16, 16), 256, 0, stream>>>(qb, kb, mask,
                                                            g * 1024, csum);
            pv_mfma<<<dim3(16, 16), 256, 0, stream>>>(qb, kb, vtb, mask,
                                                      g * 1024, csum, H, g * 1024);
        }
        tailcopy<<<dim3(64), 256, 0, stream>>>((const us8*)(H + (size_t)8064 * 1024),
                                               (us8*)hcopy);
        for (int i = 0; i < 6; i++)
            gemm_mfma<1, 1><<<dim3(8, casc[i][1]), 256, 0, stream>>>(
                H, w_out, w_out, w_out, b_out, b_out, b_out, nullptr, nullptr,
                nullptr, outp, x, 0, casc[i][0], 0, 0);
        gemm_mfma<1, 1><<<dim3(8, 1), 256, 0, stream>>>(
            hcopy, w_out, w_out, w_out, b_out, b_out, b_out, nullptr, nullptr,
            nullptr, outp, x, 0, 8064, 8064, 0);
    }
}